// Round 5
// baseline (585.081 us; speedup 1.0000x reference)
//
#include <hip/hip_runtime.h>
#include <hip/hip_bf16.h>
#include <math.h>

// Problem constants
#define BB 8
#define SS 1024
#define DD 2048
#define HH 16
#define DHD 128

typedef float  v4f  __attribute__((ext_vector_type(4)));
typedef short  v4s  __attribute__((ext_vector_type(4)));
typedef short  v8s  __attribute__((ext_vector_type(8)));
typedef __bf16 v8bf __attribute__((ext_vector_type(8)));

#define GLOBAL_AS __attribute__((address_space(1)))
#define LDS_AS    __attribute__((address_space(3)))

__device__ __forceinline__ v8bf ldsv8(const unsigned short* p) {
    return __builtin_bit_cast(v8bf, *(const v8s*)p);
}

// bf16 bits via compiler-native cast (emits v_cvt_pk_bf16_f32 pairs, RNE)
__device__ __forceinline__ short bfb(float x) {
    return __builtin_bit_cast(short, (__bf16)x);
}

// ---------------------------------------------------------------------------
// W (K x N fp32, row-major) -> WT (N x K bf16, row-major), x3 via blockIdx.z.
// ---------------------------------------------------------------------------
__global__ __launch_bounds__(256) void wtrans_all(const float* __restrict__ W0,
                                                  const float* __restrict__ W1,
                                                  const float* __restrict__ W2,
                                                  unsigned short* __restrict__ T0,
                                                  unsigned short* __restrict__ T1,
                                                  unsigned short* __restrict__ T2) {
    const float* W = blockIdx.z == 0 ? W0 : (blockIdx.z == 1 ? W1 : W2);
    unsigned short* WT = blockIdx.z == 0 ? T0 : (blockIdx.z == 1 ? T1 : T2);
    __shared__ float t[64][65];
    int nb = blockIdx.x * 64;
    int kb = blockIdx.y * 64;
    int tr = threadIdx.x >> 4;         // 0..15
    int tc = (threadIdx.x & 15) * 4;   // 0..60
#pragma unroll
    for (int i = 0; i < 4; i++) {
        int k = kb + tr + i * 16;
        v4f v = *(const v4f*)(W + (size_t)k * DD + nb + tc);
        t[tr + i * 16][tc + 0] = v[0];
        t[tr + i * 16][tc + 1] = v[1];
        t[tr + i * 16][tc + 2] = v[2];
        t[tr + i * 16][tc + 3] = v[3];
    }
    __syncthreads();
#pragma unroll
    for (int i = 0; i < 4; i++) {
        int n = nb + tr + i * 16;
        v4s o;
#pragma unroll
        for (int j = 0; j < 4; j++) o[j] = bfb(t[tc + j][tr + i * 16]);
        *(v4s*)(WT + (size_t)n * DD + kb + tc) = o;
    }
}

// ---------------------------------------------------------------------------
// Merged 3-projection GEMM, 256x256-tile, BK=64, 8-wave, double-buffered.
//   C[m][n] = sum_k bf16(A[m][k]) * BT[n][k]
// A is RAW FP32 (cvt kernels deleted): A staged global->reg->cvt->ds_write,
// producing the SAME LDS image as the old global_load_lds path (linear dest,
// chunk c_phys at row r holds logical chunk c_phys^(r&7); since rows are
// 8-aligned per instr-group, global chunk = l7^l3 as before). ds_write dest
// = base + lane*16B -> contiguous 1KB, conflict-free. B (bf16 from wtrans)
// keeps global_load_lds with the same global-side XOR swizzle.
//
// Per tile t (stages t+1):
//  p0: STAGE_B x2 (lds-direct) + ALOAD (8x dwordx4 f32 -> regs); LDA0,LDB0,MMA(0,0)
//  p1: LDB1, MMA(0,1)
//  p2: AWRITE x2 (cvt_pk + 4x ds_write_b128; compiler inserts vmcnt for regs),
//      LDA1, MMA(1,1), lgkmcnt(0) [commit writes before publishing barrier]
//  p3: LDB0, MMA(1,0), vmcnt(0) [B lds-loads from p0 long retired]
// One barrier per phase. Loads issue p0 -> consumed p2 (~1400 cyc cover).
//
// Grid: dim3(256, 3); blockIdx.y = projection {q,k,v}. XCD-chunked map on x:
// XCD x owns bm-panels [4x,4x+4) x all 8 bn-panels (A panel L2-resident).
// ---------------------------------------------------------------------------

#define STAGE_B(bb, gg, tt) do {                                              \
    __builtin_amdgcn_global_load_lds(                                         \
        (const GLOBAL_AS void*)(pB0 + (size_t)(gg) * 32 * DD + (size_t)(tt) * 64), \
        (LDS_AS void*)(&sB[(bb) * 16384 + ldsB0 + (gg) * 2048]), 16, 0, 0);   \
    __builtin_amdgcn_global_load_lds(                                         \
        (const GLOBAL_AS void*)(pB1 + (size_t)(gg) * 32 * DD + (size_t)(tt) * 64), \
        (LDS_AS void*)(&sB[(bb) * 16384 + ldsB1 + (gg) * 2048]), 16, 0, 0);   \
} while (0)

#define ALOAD(tt) do {                                                        \
    ar[0][0][0] = *(const v4f*)(qA0 + (size_t)(tt) * 64);                     \
    ar[0][0][1] = *(const v4f*)(qA0 + (size_t)(tt) * 64 + 4);                 \
    ar[0][1][0] = *(const v4f*)(qA1 + (size_t)(tt) * 64);                     \
    ar[0][1][1] = *(const v4f*)(qA1 + (size_t)(tt) * 64 + 4);                 \
    ar[1][0][0] = *(const v4f*)(qA0 + (size_t)64 * DD + (size_t)(tt) * 64);   \
    ar[1][0][1] = *(const v4f*)(qA0 + (size_t)64 * DD + (size_t)(tt) * 64 + 4); \
    ar[1][1][0] = *(const v4f*)(qA1 + (size_t)64 * DD + (size_t)(tt) * 64);   \
    ar[1][1][1] = *(const v4f*)(qA1 + (size_t)64 * DD + (size_t)(tt) * 64 + 4); \
} while (0)

#define PACK8(dst, va, vb) do {                                               \
    v8s _o;                                                                   \
    _o[0] = bfb((va)[0]); _o[1] = bfb((va)[1]);                               \
    _o[2] = bfb((va)[2]); _o[3] = bfb((va)[3]);                               \
    _o[4] = bfb((vb)[0]); _o[5] = bfb((vb)[1]);                               \
    _o[6] = bfb((vb)[2]); _o[7] = bfb((vb)[3]);                               \
    *(v8s*)(dst) = _o;                                                        \
} while (0)

#define AWRITE(bb, gg) do {                                                   \
    PACK8(&sA[(bb) * 16384 + (raA0 + (gg) * 64 + l3) * 64 + l7 * 8],          \
          ar[gg][0][0], ar[gg][0][1]);                                        \
    PACK8(&sA[(bb) * 16384 + (raA1 + (gg) * 64 + l3) * 64 + l7 * 8],          \
          ar[gg][1][0], ar[gg][1][1]);                                        \
} while (0)

#define LDA(mh) do {                                                          \
    _Pragma("unroll")                                                         \
    for (int i = 0; i < 4; i++) {                                             \
        af[i][0] = ldsv8(sAb + aRow + (mh) * 4096 + i * 1024 + c0);           \
        af[i][1] = ldsv8(sAb + aRow + (mh) * 4096 + i * 1024 + c1);           \
    }                                                                         \
} while (0)

#define LDB(nh) do {                                                          \
    _Pragma("unroll")                                                         \
    for (int j = 0; j < 2; j++) {                                             \
        bf2[j][0] = ldsv8(sBb + bRow + (nh) * 2048 + j * 1024 + c0);          \
        bf2[j][1] = ldsv8(sBb + bRow + (nh) * 2048 + j * 1024 + c1);          \
    }                                                                         \
} while (0)

#define MMA(mh, nh) do {                                                      \
    _Pragma("unroll")                                                         \
    for (int i = 0; i < 4; i++) {                                             \
        _Pragma("unroll")                                                     \
        for (int j = 0; j < 2; j++)                                           \
            acc[(mh) * 4 + i][(nh) * 2 + j] =                                 \
                __builtin_amdgcn_mfma_f32_16x16x32_bf16(                      \
                    af[i][0], bf2[j][0], acc[(mh) * 4 + i][(nh) * 2 + j], 0, 0, 0); \
    }                                                                         \
    _Pragma("unroll")                                                         \
    for (int i = 0; i < 4; i++) {                                             \
        _Pragma("unroll")                                                     \
        for (int j = 0; j < 2; j++)                                           \
            acc[(mh) * 4 + i][(nh) * 2 + j] =                                 \
                __builtin_amdgcn_mfma_f32_16x16x32_bf16(                      \
                    af[i][1], bf2[j][1], acc[(mh) * 4 + i][(nh) * 2 + j], 0, 0, 0); \
    }                                                                         \
} while (0)

#define QSCALE 0.12753139626246937f  // log2(e)/sqrt(128)

__global__ __launch_bounds__(512, 2) void gemm_all(
        const float* __restrict__ Aq, const float* __restrict__ Ak,
        const float* __restrict__ Av,
        const unsigned short* __restrict__ Bq, const unsigned short* __restrict__ Bk,
        const unsigned short* __restrict__ Bv,
        unsigned short* __restrict__ Cq, unsigned short* __restrict__ Ck,
        unsigned short* __restrict__ Cv) {
    __shared__ __align__(16) unsigned short sA[2 * 16384];   // 2 x 256 x 64
    __shared__ __align__(16) unsigned short sB[2 * 16384];

    const int proj = blockIdx.y;
    const float* A; const unsigned short* BT; unsigned short* C;
    float scale; int vmode;
    if (proj == 0)      { A = Aq; BT = Bq; C = Cq; scale = QSCALE; vmode = 0; }
    else if (proj == 1) { A = Ak; BT = Bk; C = Ck; scale = 1.f;    vmode = 0; }
    else                { A = Av; BT = Bv; C = Cv; scale = 1.f;    vmode = 1; }

    const int tid  = threadIdx.x;
    const int lane = tid & 63;
    const int w    = tid >> 6;        // 0..7
    const int qcol = lane & 15;
    const int quad = lane >> 4;
    const int l3   = lane >> 3;       // 0..7
    const int l7   = lane & 7;

    // XCD-chunked grid map: XCD x = bid%8 owns bm-panels [4x,4x+4) x all bn.
    const int bid = blockIdx.x;
    const int bm  = ((bid & 7) * 4 + ((bid >> 3) & 3)) * 256;
    const int bn  = (bid >> 5) * 256;

    const int wm = (w >> 2) * 128;    // 0 / 128
    const int wn = (w & 3) * 64;      // 0..192

    // --- staging geometry: inst = w*2+jj (0..15), 8 rows x 1 chunk-row each ---
    const int gchunk = (l7 ^ l3) * 8;           // logical chunk (elements)
    const int iA0 = w * 2, iA1 = w * 2 + 1;
    const int raA0 = (iA0 >> 3) * 128 + (iA0 & 7) * 8;
    const int raA1 = (iA1 >> 3) * 128 + (iA1 & 7) * 8;
    const int rbB0 = (iA0 >> 2) * 64 + (iA0 & 3) * 8;
    const int rbB1 = (iA1 >> 2) * 64 + (iA1 & 3) * 8;
    const float* qA0 = A + (size_t)(bm + raA0 + l3) * DD + gchunk;   // f32
    const float* qA1 = A + (size_t)(bm + raA1 + l3) * DD + gchunk;
    const unsigned short* pB0 = BT + (size_t)(bn + rbB0 + l3) * DD + gchunk;
    const unsigned short* pB1 = BT + (size_t)(bn + rbB1 + l3) * DD + gchunk;
    const int ldsB0 = rbB0 * 64, ldsB1 = rbB1 * 64;

    // --- fragment-read constants ---
    const int c0   = ((quad ^ l7) & 7) * 8;   // ks=0 phys chunk (ushort off)
    const int c1   = c0 ^ 32;                 // ks=1 (logical ^4 chunks)
    const int aRow = (wm + qcol) * 64;
    const int bRow = (wn + qcol) * 64;

    v4f acc[8][4];
#pragma unroll
    for (int i = 0; i < 8; i++)
#pragma unroll
        for (int j = 0; j < 4; j++) acc[i][j] = (v4f){0.f, 0.f, 0.f, 0.f};

    v8bf af[4][2];    // A frags of current mh
    v8bf bf2[2][2];   // B frags of current nh
    v4f  ar[2][2][2]; // in-flight A f32 (g, jj, half) — static indices only

    const int nt = DD >> 6;   // 32 K-tiles

    // --- prologue: fully stage tile0 into buf0 ---
    STAGE_B(0, 0, 0);
    STAGE_B(0, 1, 0);
    ALOAD(0);
    AWRITE(0, 0);
    AWRITE(0, 1);
    asm volatile("s_waitcnt vmcnt(0) lgkmcnt(0)");
    __builtin_amdgcn_s_barrier();

    for (int t = 0; t < nt - 1; ++t) {
        const int buf = t & 1, nbuf = buf ^ 1;
        const unsigned short* sAb = &sA[buf * 16384];
        const unsigned short* sBb = &sB[buf * 16384];

        // p0: stage B(t+1) + issue A loads(t+1); compute (0,0)
        STAGE_B(nbuf, 0, t + 1);
        STAGE_B(nbuf, 1, t + 1);
        ALOAD(t + 1);
        LDA(0); LDB(0);
        MMA(0, 0);
        __builtin_amdgcn_s_barrier();

        // p1: (0,1)
        LDB(1);
        MMA(0, 1);
        __builtin_amdgcn_s_barrier();

        // p2: cvt+write A(t+1) into nbuf; compute (1,1)
        AWRITE(nbuf, 0);
        AWRITE(nbuf, 1);
        LDA(1);
        MMA(1, 1);
        asm volatile("s_waitcnt lgkmcnt(0)");   // commit ds_writes
        __builtin_amdgcn_s_barrier();

        // p3: (1,0); retire B lds-loads (issued p0, ~3 phases ago)
        LDB(0);
        MMA(1, 0);
        asm volatile("s_waitcnt vmcnt(0)");
        __builtin_amdgcn_s_barrier();
    }

    // --- peeled last tile: no staging ---
    {
        const int buf = (nt - 1) & 1;
        const unsigned short* sAb = &sA[buf * 16384];
        const unsigned short* sBb = &sB[buf * 16384];
        LDA(0); LDB(0); MMA(0, 0);
        LDB(1);         MMA(0, 1);
        LDA(1);         MMA(1, 1);
        LDB(0);         MMA(1, 0);
    }

    // ---- epilogue ----
    if (vmode == 0) {
#pragma unroll
        for (int mi = 0; mi < 8; mi++)
#pragma unroll
            for (int nj = 0; nj < 4; nj++)
#pragma unroll
                for (int r = 0; r < 4; r++) {
                    int row = bm + wm + mi * 16 + quad * 4 + r;
                    int col = bn + wn + nj * 16 + qcol;
                    C[(size_t)row * DD + col] = (unsigned short)bfb(acc[mi][nj][r] * scale);
                }
    } else {
#pragma unroll
        for (int mi = 0; mi < 8; mi++)
#pragma unroll
            for (int nj = 0; nj < 4; nj++)
#pragma unroll
                for (int r = 0; r < 4; r++) {
                    int row = bm + wm + mi * 16 + quad * 4 + r;
                    int col = bn + wn + nj * 16 + qcol;
                    size_t idx = ((size_t)(row >> 10) * 2048 + col) * 1024 + (row & 1023);
                    C[idx] = (unsigned short)bfb(acc[mi][nj][r] * scale);
                }
    }
}

// ---------------------------------------------------------------------------
// Flash attention v5: PV via per-wave LDS P slice, 16x mfma_16x16x32 (r4);
// P pack now uses compiler-native bf16 casts (v_cvt_pk_bf16_f32) instead of
// 4-op manual RNE — cuts ~56 VALU instrs/tile/wave from the softmax path.
//
// K/V staging swizzle (global-side XOR, LDS dest linear):
//   sK[key][chunk c] = K[key][c ^ (key&15)]   (16 chunks of 16B per row)
//   sV[d][chunk c]   = V^T[d][c ^ (d&7)]      (8 chunks of 16B per row)
// ---------------------------------------------------------------------------
__global__ __launch_bounds__(256, 4) void attn_kernel(const unsigned short* __restrict__ qh,
                                                      const unsigned short* __restrict__ kh,
                                                      const unsigned short* __restrict__ vt,
                                                      float* __restrict__ out) {
    __shared__ __align__(16) unsigned short sK[64 * 128];   // [key][d]
    __shared__ __align__(16) unsigned short sV[128 * 64];   // [d][key]
    __shared__ __align__(16) unsigned short sP[4 * 16 * 64]; // per-wave [q][key]

    int lane = threadIdx.x & 63, w = threadIdx.x >> 6;
    int b = blockIdx.z, h = blockIdx.y;
    int q0 = blockIdx.x * 64 + w * 16;
    int qcol = lane & 15, quad = lane >> 4;

    // Q fragments (B-operand of 16x16x32): n = q = lane&15, k = d
    const unsigned short* qp = qh + (size_t)(b * SS + q0 + qcol) * DD + h * DHD;
    v8bf bq[4];
#pragma unroll
    for (int kk = 0; kk < 4; kk++)
        bq[kk] = __builtin_bit_cast(v8bf, *(const v8s*)(qp + kk * 32 + quad * 8));

    // --- staging addresses (element offsets within current tile) ---
    int ko[4];
#pragma unroll
    for (int j = 0; j < 4; j++) {
        int key = w * 16 + j * 4 + (lane >> 4);
        ko[j] = key * DD + (((lane & 15) ^ (key & 15)) * 8);
    }
    int vo0 = (w * 32 + (lane >> 3)) * SS + (((lane & 7) ^ (lane >> 3)) * 8);

    const unsigned short* kcur = kh + (size_t)b * SS * DD + h * DHD;
    const unsigned short* vcur = vt + (size_t)(b * HH + h) * DHD * SS;
    unsigned short* kl0 = &sK[(w * 16) * 128];
    unsigned short* vl0 = &sV[(w * 32) * 64];
    unsigned short* sPw = &sP[w * 1024];

    // P LDS addresses (loop-invariant): write 4x b64, read 2x b128
    int pw[4], pr[2];
#pragma unroll
    for (int kf = 0; kf < 4; kf++)
        pw[kf] = qcol * 64 + (((kf * 2 + (quad >> 1)) ^ (qcol & 7)) * 8) + (quad & 1) * 4;
#pragma unroll
    for (int ks = 0; ks < 2; ks++)
        pr[ks] = qcol * 64 + (((ks * 4 + quad) ^ (qcol & 7)) * 8);

    float m_i = -1e30f, l_i = 0.f;
    v4f acc[8];
#pragma unroll
    for (int c = 0; c < 8; c++) acc[c] = (v4f){0.f, 0.f, 0.f, 0.f};

    for (int kb = 0; kb < SS; kb += 64) {
        __syncthreads();   // previous tile's LDS reads complete
#pragma unroll
        for (int j = 0; j < 4; j++)
            __builtin_amdgcn_global_load_lds((const GLOBAL_AS void*)(kcur + ko[j]),
                                             (LDS_AS void*)(kl0 + j * 4 * 128), 16, 0, 0);
#pragma unroll
        for (int j = 0; j < 4; j++)
            __builtin_amdgcn_global_load_lds((const GLOBAL_AS void*)(vcur + vo0 + j * 8 * SS),
                                             (LDS_AS void*)(vl0 + j * 8 * 64), 16, 0, 0);
        kcur += (size_t)64 * DD;
        vcur += 64;
        __syncthreads();   // staging drained

        // S^T = K.Q^T : 16 MFMA 16x16x32, fragments from swizzled sK
        v4f s[4];
#pragma unroll
        for (int kf = 0; kf < 4; kf++) {
            s[kf] = (v4f){0.f, 0.f, 0.f, 0.f};
#pragma unroll
            for (int kk = 0; kk < 4; kk++) {
                v8bf ak = __builtin_bit_cast(v8bf,
                    *(const v8s*)&sK[(kf * 16 + qcol) * 128 + (((kk * 4 + quad) ^ qcol) * 8)]);
                s[kf] = __builtin_amdgcn_mfma_f32_16x16x32_bf16(ak, bq[kk], s[kf], 0, 0, 0);
            }
        }

        // online softmax over 64 keys (base-2; log2(e) folded into qh scale)
        float mx = -1e30f;
#pragma unroll
        for (int kf = 0; kf < 4; kf++)
#pragma unroll
            for (int r = 0; r < 4; r++) mx = fmaxf(mx, s[kf][r]);
        mx = fmaxf(mx, __shfl_xor(mx, 16));
        mx = fmaxf(mx, __shfl_xor(mx, 32));
        float m_new = fmaxf(m_i, mx);
        float rs = 0.f;
        v4s p[4];
#pragma unroll
        for (int kf = 0; kf < 4; kf++)
#pragma unroll
            for (int r = 0; r < 4; r++) {
                float pf = exp2f(s[kf][r] - m_new);
                rs += pf;
                p[kf][r] = bfb(pf);
            }
        rs += __shfl_xor(rs, 16);
        rs += __shfl_xor(rs, 32);
        if (__any(mx > m_i)) {          // skip O-rescale when no max grew
            float alpha = exp2f(m_i - m_new);
            l_i *= alpha;
#pragma unroll
            for (int c = 0; c < 8; c++) {
                acc[c][0] *= alpha; acc[c][1] *= alpha;
                acc[c][2] *= alpha; acc[c][3] *= alpha;
            }
        }
        l_i += rs;
        m_i = m_new;

        // P -> LDS (own wave slice), then PV: 16 MFMA 16x16x32
#pragma unroll
        for (int kf = 0; kf < 4; kf++)
            *(v4s*)&sPw[pw[kf]] = p[kf];

#pragma unroll
        for (int ks = 0; ks < 2; ks++) {
            v8bf pb = ldsv8(&sPw[pr[ks]]);
#pragma unroll
            for (int c = 0; c < 8; c++) {
                v8bf av = ldsv8(&sV[(c * 16 + qcol) * 64 + (((ks * 4 + quad) ^ (qcol & 7)) * 8)]);
                acc[c] = __builtin_amdgcn_mfma_f32_16x16x32_bf16(av, pb, acc[c], 0, 0, 0);
            }
        }
    }

    float rl = 1.0f / l_i;
    float* op = out + (size_t)(b * SS + q0 + qcol) * DD + h * DHD;
#pragma unroll
    for (int c = 0; c < 8; c++)
#pragma unroll
        for (int r = 0; r < 4; r++)
            op[c * 16 + quad * 4 + r] = acc[c][r] * rl;
}

// ---------------------------------------------------------------------------
// Launch. ws layout (needs 120 MB):
//   wq @ 0 MB (8) | wk @ 8 (8) | wv @ 16 (8) | qh @ 24 (32) | kh @ 56 (32)
//   | vt @ 88 (32)
// 3 dispatches total: wtrans_all, gemm_all, attn_kernel.
// ---------------------------------------------------------------------------
extern "C" void kernel_launch(void* const* d_in, const int* in_sizes, int n_in,
                              void* d_out, int out_size, void* d_ws, size_t ws_size,
                              hipStream_t stream) {
    const float* q  = (const float*)d_in[0];
    const float* k  = (const float*)d_in[1];
    const float* v  = (const float*)d_in[2];
    const float* Wq = (const float*)d_in[3];
    const float* Wk = (const float*)d_in[4];
    const float* Wv = (const float*)d_in[5];
    char* ws = (char*)d_ws;
    unsigned short* wq  = (unsigned short*)(ws);
    unsigned short* wk  = (unsigned short*)(ws + (size_t)8  * 1024 * 1024);
    unsigned short* wv  = (unsigned short*)(ws + (size_t)16 * 1024 * 1024);
    unsigned short* qhb = (unsigned short*)(ws + (size_t)24 * 1024 * 1024);
    unsigned short* khb = (unsigned short*)(ws + (size_t)56 * 1024 * 1024);
    unsigned short* vtb = (unsigned short*)(ws + (size_t)88 * 1024 * 1024);
    float* out = (float*)d_out;

    wtrans_all<<<dim3(32, 32, 3), dim3(256), 0, stream>>>(Wq, Wk, Wv, wq, wk, wv);
    gemm_all<<<dim3(256, 3), dim3(512), 0, stream>>>(q, k, v, wq, wk, wv, qhb, khb, vtb);
    attn_kernel<<<dim3(SS / 64, HH, BB), dim3(256), 0, stream>>>(qhb, khb, vtb, out);
}

// Round 6
// 556.588 us; speedup vs baseline: 1.0512x; 1.0512x over previous
//
#include <hip/hip_runtime.h>
#include <hip/hip_bf16.h>
#include <math.h>

// Problem constants
#define BB 8
#define SS 1024
#define DD 2048
#define HH 16
#define DHD 128

typedef float  v4f  __attribute__((ext_vector_type(4)));
typedef short  v4s  __attribute__((ext_vector_type(4)));
typedef short  v8s  __attribute__((ext_vector_type(8)));
typedef __bf16 v8bf __attribute__((ext_vector_type(8)));

#define GLOBAL_AS __attribute__((address_space(1)))
#define LDS_AS    __attribute__((address_space(3)))

__device__ __forceinline__ v8bf ldsv8(const unsigned short* p) {
    return __builtin_bit_cast(v8bf, *(const v8s*)p);
}

// bf16 bits via compiler-native cast (v_cvt_pk_bf16_f32, RNE)
__device__ __forceinline__ short bfb(float x) {
    return __builtin_bit_cast(short, (__bf16)x);
}

// manual RNE bf16 (r4 attn measured 128 us with this; kept for attn to
// isolate variables)
__device__ __forceinline__ unsigned short f2b(float f) {
    union { float f; unsigned int u; } x; x.f = f;
    unsigned int r = x.u + 0x7fffu + ((x.u >> 16) & 1u);
    return (unsigned short)(r >> 16);
}

// ---------------------------------------------------------------------------
// W (K x N fp32, row-major) -> WT (N x K bf16, row-major), x3 via blockIdx.z.
// ---------------------------------------------------------------------------
__global__ __launch_bounds__(256) void wtrans_all(const float* __restrict__ W0,
                                                  const float* __restrict__ W1,
                                                  const float* __restrict__ W2,
                                                  unsigned short* __restrict__ T0,
                                                  unsigned short* __restrict__ T1,
                                                  unsigned short* __restrict__ T2) {
    const float* W = blockIdx.z == 0 ? W0 : (blockIdx.z == 1 ? W1 : W2);
    unsigned short* WT = blockIdx.z == 0 ? T0 : (blockIdx.z == 1 ? T1 : T2);
    __shared__ float t[64][65];
    int nb = blockIdx.x * 64;
    int kb = blockIdx.y * 64;
    int tr = threadIdx.x >> 4;         // 0..15
    int tc = (threadIdx.x & 15) * 4;   // 0..60
#pragma unroll
    for (int i = 0; i < 4; i++) {
        int k = kb + tr + i * 16;
        v4f v = *(const v4f*)(W + (size_t)k * DD + nb + tc);
        t[tr + i * 16][tc + 0] = v[0];
        t[tr + i * 16][tc + 1] = v[1];
        t[tr + i * 16][tc + 2] = v[2];
        t[tr + i * 16][tc + 3] = v[3];
    }
    __syncthreads();
#pragma unroll
    for (int i = 0; i < 4; i++) {
        int n = nb + tr + i * 16;
        v4s o;
#pragma unroll
        for (int j = 0; j < 4; j++) o[j] = bfb(t[tc + j][tr + i * 16]);
        *(v4s*)(WT + (size_t)n * DD + kb + tc) = o;
    }
}

// ---------------------------------------------------------------------------
// Merged 3-projection GEMM, 256x256-tile, BK=64, 8-wave, double-buffered.
//   C[m][n] = sum_k bf16(A[m][k]) * BT[n][k]
//
// Round-6: ONE s_barrier per tile (was 4). All intra-tile reads hit the
// stable buf, all writes hit nbuf -> no cross-wave hazard inside a tile.
// A zero-cost sched_barrier(0) at the midpoint bounds register hoisting.
// The compiler is free to interleave 28 ds_reads + 8 global loads + cvt
// VALU across the tile's 64 MFMAs (m196: the fine interleave is the lever;
// per-quadrant barriers were walls).
//
// A staged global->reg->cvt->ds_write at TILE END (A-loads issued at tile
// top get ~a full tile of latency cover; DS pipe is in-order per wave, and
// lgkmcnt(0)+barrier publish the writes before the next tile's reads).
// B (bf16 from wtrans) via global_load_lds with global-side XOR swizzle.
//
// Grid: dim3(256, 3); blockIdx.y = projection {q,k,v}. XCD-chunked map on x.
// ---------------------------------------------------------------------------

#define STAGE_B(bb, gg, tt) do {                                              \
    __builtin_amdgcn_global_load_lds(                                         \
        (const GLOBAL_AS void*)(pB0 + (size_t)(gg) * 32 * DD + (size_t)(tt) * 64), \
        (LDS_AS void*)(&sB[(bb) * 16384 + ldsB0 + (gg) * 2048]), 16, 0, 0);   \
    __builtin_amdgcn_global_load_lds(                                         \
        (const GLOBAL_AS void*)(pB1 + (size_t)(gg) * 32 * DD + (size_t)(tt) * 64), \
        (LDS_AS void*)(&sB[(bb) * 16384 + ldsB1 + (gg) * 2048]), 16, 0, 0);   \
} while (0)

#define ALOAD(tt) do {                                                        \
    ar[0][0][0] = *(const v4f*)(qA0 + (size_t)(tt) * 64);                     \
    ar[0][0][1] = *(const v4f*)(qA0 + (size_t)(tt) * 64 + 4);                 \
    ar[0][1][0] = *(const v4f*)(qA1 + (size_t)(tt) * 64);                     \
    ar[0][1][1] = *(const v4f*)(qA1 + (size_t)(tt) * 64 + 4);                 \
    ar[1][0][0] = *(const v4f*)(qA0 + (size_t)64 * DD + (size_t)(tt) * 64);   \
    ar[1][0][1] = *(const v4f*)(qA0 + (size_t)64 * DD + (size_t)(tt) * 64 + 4); \
    ar[1][1][0] = *(const v4f*)(qA1 + (size_t)64 * DD + (size_t)(tt) * 64);   \
    ar[1][1][1] = *(const v4f*)(qA1 + (size_t)64 * DD + (size_t)(tt) * 64 + 4); \
} while (0)

#define PACK8(dst, va, vb) do {                                               \
    v8s _o;                                                                   \
    _o[0] = bfb((va)[0]); _o[1] = bfb((va)[1]);                               \
    _o[2] = bfb((va)[2]); _o[3] = bfb((va)[3]);                               \
    _o[4] = bfb((vb)[0]); _o[5] = bfb((vb)[1]);                               \
    _o[6] = bfb((vb)[2]); _o[7] = bfb((vb)[3]);                               \
    *(v8s*)(dst) = _o;                                                        \
} while (0)

#define AWRITE(bb, gg) do {                                                   \
    PACK8(&sA[(bb) * 16384 + (raA0 + (gg) * 64 + l3) * 64 + l7 * 8],          \
          ar[gg][0][0], ar[gg][0][1]);                                        \
    PACK8(&sA[(bb) * 16384 + (raA1 + (gg) * 64 + l3) * 64 + l7 * 8],          \
          ar[gg][1][0], ar[gg][1][1]);                                        \
} while (0)

#define LDA(mh) do {                                                          \
    _Pragma("unroll")                                                         \
    for (int i = 0; i < 4; i++) {                                             \
        af[i][0] = ldsv8(sAb + aRow + (mh) * 4096 + i * 1024 + c0);           \
        af[i][1] = ldsv8(sAb + aRow + (mh) * 4096 + i * 1024 + c1);           \
    }                                                                         \
} while (0)

#define LDB(nh) do {                                                          \
    _Pragma("unroll")                                                         \
    for (int j = 0; j < 2; j++) {                                             \
        bf2[j][0] = ldsv8(sBb + bRow + (nh) * 2048 + j * 1024 + c0);          \
        bf2[j][1] = ldsv8(sBb + bRow + (nh) * 2048 + j * 1024 + c1);          \
    }                                                                         \
} while (0)

#define MMA(mh, nh) do {                                                      \
    _Pragma("unroll")                                                         \
    for (int i = 0; i < 4; i++) {                                             \
        _Pragma("unroll")                                                     \
        for (int j = 0; j < 2; j++)                                           \
            acc[(mh) * 4 + i][(nh) * 2 + j] =                                 \
                __builtin_amdgcn_mfma_f32_16x16x32_bf16(                      \
                    af[i][0], bf2[j][0], acc[(mh) * 4 + i][(nh) * 2 + j], 0, 0, 0); \
    }                                                                         \
    _Pragma("unroll")                                                         \
    for (int i = 0; i < 4; i++) {                                             \
        _Pragma("unroll")                                                     \
        for (int j = 0; j < 2; j++)                                           \
            acc[(mh) * 4 + i][(nh) * 2 + j] =                                 \
                __builtin_amdgcn_mfma_f32_16x16x32_bf16(                      \
                    af[i][1], bf2[j][1], acc[(mh) * 4 + i][(nh) * 2 + j], 0, 0, 0); \
    }                                                                         \
} while (0)

#define QSCALE 0.12753139626246937f  // log2(e)/sqrt(128)

__global__ __launch_bounds__(512, 2) void gemm_all(
        const float* __restrict__ Aq, const float* __restrict__ Ak,
        const float* __restrict__ Av,
        const unsigned short* __restrict__ Bq, const unsigned short* __restrict__ Bk,
        const unsigned short* __restrict__ Bv,
        unsigned short* __restrict__ Cq, unsigned short* __restrict__ Ck,
        unsigned short* __restrict__ Cv) {
    __shared__ __align__(16) unsigned short sA[2 * 16384];   // 2 x 256 x 64
    __shared__ __align__(16) unsigned short sB[2 * 16384];

    const int proj = blockIdx.y;
    const float* A; const unsigned short* BT; unsigned short* C;
    float scale; int vmode;
    if (proj == 0)      { A = Aq; BT = Bq; C = Cq; scale = QSCALE; vmode = 0; }
    else if (proj == 1) { A = Ak; BT = Bk; C = Ck; scale = 1.f;    vmode = 0; }
    else                { A = Av; BT = Bv; C = Cv; scale = 1.f;    vmode = 1; }

    const int tid  = threadIdx.x;
    const int lane = tid & 63;
    const int w    = tid >> 6;        // 0..7
    const int qcol = lane & 15;
    const int quad = lane >> 4;
    const int l3   = lane >> 3;       // 0..7
    const int l7   = lane & 7;

    // XCD-chunked grid map: XCD x = bid%8 owns bm-panels [4x,4x+4) x all bn.
    const int bid = blockIdx.x;
    const int bm  = ((bid & 7) * 4 + ((bid >> 3) & 3)) * 256;
    const int bn  = (bid >> 5) * 256;

    const int wm = (w >> 2) * 128;    // 0 / 128
    const int wn = (w & 3) * 64;      // 0..192

    // --- staging geometry: inst = w*2+jj (0..15), 8 rows x 1 chunk each ---
    const int gchunk = (l7 ^ l3) * 8;           // logical chunk (elements)
    const int iA0 = w * 2, iA1 = w * 2 + 1;
    const int raA0 = (iA0 >> 3) * 128 + (iA0 & 7) * 8;
    const int raA1 = (iA1 >> 3) * 128 + (iA1 & 7) * 8;
    const int rbB0 = (iA0 >> 2) * 64 + (iA0 & 3) * 8;
    const int rbB1 = (iA1 >> 2) * 64 + (iA1 & 3) * 8;
    const float* qA0 = A + (size_t)(bm + raA0 + l3) * DD + gchunk;   // f32
    const float* qA1 = A + (size_t)(bm + raA1 + l3) * DD + gchunk;
    const unsigned short* pB0 = BT + (size_t)(bn + rbB0 + l3) * DD + gchunk;
    const unsigned short* pB1 = BT + (size_t)(bn + rbB1 + l3) * DD + gchunk;
    const int ldsB0 = rbB0 * 64, ldsB1 = rbB1 * 64;

    // --- fragment-read constants ---
    const int c0   = ((quad ^ l7) & 7) * 8;   // ks=0 phys chunk (ushort off)
    const int c1   = c0 ^ 32;                 // ks=1 (logical ^4 chunks)
    const int aRow = (wm + qcol) * 64;
    const int bRow = (wn + qcol) * 64;

    v4f acc[8][4];
#pragma unroll
    for (int i = 0; i < 8; i++)
#pragma unroll
        for (int j = 0; j < 4; j++) acc[i][j] = (v4f){0.f, 0.f, 0.f, 0.f};

    v8bf af[4][2];    // A frags of current mh
    v8bf bf2[2][2];   // B frags of current nh
    v4f  ar[2][2][2]; // in-flight A f32 (g, jj, half) — static indices only

    const int nt = DD >> 6;   // 32 K-tiles

    // --- prologue: fully stage tile0 into buf0 ---
    STAGE_B(0, 0, 0);
    STAGE_B(0, 1, 0);
    ALOAD(0);
    AWRITE(0, 0);
    AWRITE(0, 1);
    asm volatile("s_waitcnt vmcnt(0) lgkmcnt(0)");
    __builtin_amdgcn_s_barrier();

    for (int t = 0; t < nt - 1; ++t) {
        const int buf = t & 1, nbuf = buf ^ 1;
        const unsigned short* sAb = &sA[buf * 16384];
        const unsigned short* sBb = &sB[buf * 16384];

        // staging issues first (max latency cover), then quadrants 00,01
        STAGE_B(nbuf, 0, t + 1);
        STAGE_B(nbuf, 1, t + 1);
        ALOAD(t + 1);
        LDA(0); LDB(0);
        MMA(0, 0);
        LDB(1);
        MMA(0, 1);
        __builtin_amdgcn_sched_barrier(0);   // bound hoisting; zero runtime cost
        // quadrants 11 (bf2 still = nh1), 10; then commit A into nbuf
        LDA(1);
        MMA(1, 1);
        LDB(0);
        MMA(1, 0);
        AWRITE(nbuf, 0);
        AWRITE(nbuf, 1);
        asm volatile("s_waitcnt vmcnt(0) lgkmcnt(0)");
        __builtin_amdgcn_sched_barrier(0);
        __builtin_amdgcn_s_barrier();        // single per-tile publish point
    }

    // --- peeled last tile: no staging ---
    {
        const int buf = (nt - 1) & 1;
        const unsigned short* sAb = &sA[buf * 16384];
        const unsigned short* sBb = &sB[buf * 16384];
        LDA(0); LDB(0); MMA(0, 0);
        LDB(1);         MMA(0, 1);
        LDA(1);         MMA(1, 1);
        LDB(0);         MMA(1, 0);
    }

    // ---- epilogue ----
    if (vmode == 0) {
#pragma unroll
        for (int mi = 0; mi < 8; mi++)
#pragma unroll
            for (int nj = 0; nj < 4; nj++)
#pragma unroll
                for (int r = 0; r < 4; r++) {
                    int row = bm + wm + mi * 16 + quad * 4 + r;
                    int col = bn + wn + nj * 16 + qcol;
                    C[(size_t)row * DD + col] = (unsigned short)bfb(acc[mi][nj][r] * scale);
                }
    } else {
#pragma unroll
        for (int mi = 0; mi < 8; mi++)
#pragma unroll
            for (int nj = 0; nj < 4; nj++)
#pragma unroll
                for (int r = 0; r < 4; r++) {
                    int row = bm + wm + mi * 16 + quad * 4 + r;
                    int col = bn + wn + nj * 16 + qcol;
                    size_t idx = ((size_t)(row >> 10) * 2048 + col) * 1024 + (row & 1023);
                    C[idx] = (unsigned short)bfb(acc[mi][nj][r] * scale);
                }
    }
}

// ---------------------------------------------------------------------------
// Flash attention — byte-exact r4 kernel (measured 128.4 us): PV via
// per-wave LDS P slice with 16x mfma_16x16x32; manual f2b pack; skip-rescale.
//
// K/V staging swizzle (global-side XOR, LDS dest linear):
//   sK[key][chunk c] = K[key][c ^ (key&15)]   (16 chunks of 16B per row)
//   sV[d][chunk c]   = V^T[d][c ^ (d&7)]      (8 chunks of 16B per row)
// ---------------------------------------------------------------------------
__global__ __launch_bounds__(256, 4) void attn_kernel(const unsigned short* __restrict__ qh,
                                                      const unsigned short* __restrict__ kh,
                                                      const unsigned short* __restrict__ vt,
                                                      float* __restrict__ out) {
    __shared__ __align__(16) unsigned short sK[64 * 128];   // [key][d]
    __shared__ __align__(16) unsigned short sV[128 * 64];   // [d][key]
    __shared__ __align__(16) unsigned short sP[4 * 16 * 64]; // per-wave [q][key]

    int lane = threadIdx.x & 63, w = threadIdx.x >> 6;
    int b = blockIdx.z, h = blockIdx.y;
    int q0 = blockIdx.x * 64 + w * 16;
    int qcol = lane & 15, quad = lane >> 4;

    // Q fragments (B-operand of 16x16x32): n = q = lane&15, k = d
    const unsigned short* qp = qh + (size_t)(b * SS + q0 + qcol) * DD + h * DHD;
    v8bf bq[4];
#pragma unroll
    for (int kk = 0; kk < 4; kk++)
        bq[kk] = __builtin_bit_cast(v8bf, *(const v8s*)(qp + kk * 32 + quad * 8));

    // --- staging addresses (element offsets within current tile) ---
    int ko[4];
#pragma unroll
    for (int j = 0; j < 4; j++) {
        int key = w * 16 + j * 4 + (lane >> 4);
        ko[j] = key * DD + (((lane & 15) ^ (key & 15)) * 8);
    }
    int vo0 = (w * 32 + (lane >> 3)) * SS + (((lane & 7) ^ (lane >> 3)) * 8);

    const unsigned short* kcur = kh + (size_t)b * SS * DD + h * DHD;
    const unsigned short* vcur = vt + (size_t)(b * HH + h) * DHD * SS;
    unsigned short* kl0 = &sK[(w * 16) * 128];
    unsigned short* vl0 = &sV[(w * 32) * 64];
    unsigned short* sPw = &sP[w * 1024];

    // P LDS addresses (loop-invariant): write 4x b64, read 2x b128
    int pw[4], pr[2];
#pragma unroll
    for (int kf = 0; kf < 4; kf++)
        pw[kf] = qcol * 64 + (((kf * 2 + (quad >> 1)) ^ (qcol & 7)) * 8) + (quad & 1) * 4;
#pragma unroll
    for (int ks = 0; ks < 2; ks++)
        pr[ks] = qcol * 64 + (((ks * 4 + quad) ^ (qcol & 7)) * 8);

    float m_i = -1e30f, l_i = 0.f;
    v4f acc[8];
#pragma unroll
    for (int c = 0; c < 8; c++) acc[c] = (v4f){0.f, 0.f, 0.f, 0.f};

    for (int kb = 0; kb < SS; kb += 64) {
        __syncthreads();   // previous tile's LDS reads complete
#pragma unroll
        for (int j = 0; j < 4; j++)
            __builtin_amdgcn_global_load_lds((const GLOBAL_AS void*)(kcur + ko[j]),
                                             (LDS_AS void*)(kl0 + j * 4 * 128), 16, 0, 0);
#pragma unroll
        for (int j = 0; j < 4; j++)
            __builtin_amdgcn_global_load_lds((const GLOBAL_AS void*)(vcur + vo0 + j * 8 * SS),
                                             (LDS_AS void*)(vl0 + j * 8 * 64), 16, 0, 0);
        kcur += (size_t)64 * DD;
        vcur += 64;
        __syncthreads();   // staging drained

        // S^T = K.Q^T : 16 MFMA 16x16x32, fragments from swizzled sK
        v4f s[4];
#pragma unroll
        for (int kf = 0; kf < 4; kf++) {
            s[kf] = (v4f){0.f, 0.f, 0.f, 0.f};
#pragma unroll
            for (int kk = 0; kk < 4; kk++) {
                v8bf ak = __builtin_bit_cast(v8bf,
                    *(const v8s*)&sK[(kf * 16 + qcol) * 128 + (((kk * 4 + quad) ^ qcol) * 8)]);
                s[kf] = __builtin_amdgcn_mfma_f32_16x16x32_bf16(ak, bq[kk], s[kf], 0, 0, 0);
            }
        }

        // online softmax over 64 keys (base-2; log2(e) folded into qh scale)
        float mx = -1e30f;
#pragma unroll
        for (int kf = 0; kf < 4; kf++)
#pragma unroll
            for (int r = 0; r < 4; r++) mx = fmaxf(mx, s[kf][r]);
        mx = fmaxf(mx, __shfl_xor(mx, 16));
        mx = fmaxf(mx, __shfl_xor(mx, 32));
        float m_new = fmaxf(m_i, mx);
        float rs = 0.f;
        v4s p[4];
#pragma unroll
        for (int kf = 0; kf < 4; kf++)
#pragma unroll
            for (int r = 0; r < 4; r++) {
                float pf = exp2f(s[kf][r] - m_new);
                rs += pf;
                p[kf][r] = (short)f2b(pf);
            }
        rs += __shfl_xor(rs, 16);
        rs += __shfl_xor(rs, 32);
        if (__any(mx > m_i)) {          // skip O-rescale when no max grew
            float alpha = exp2f(m_i - m_new);
            l_i *= alpha;
#pragma unroll
            for (int c = 0; c < 8; c++) {
                acc[c][0] *= alpha; acc[c][1] *= alpha;
                acc[c][2] *= alpha; acc[c][3] *= alpha;
            }
        }
        l_i += rs;
        m_i = m_new;

        // P -> LDS (own wave slice), then PV: 16 MFMA 16x16x32
#pragma unroll
        for (int kf = 0; kf < 4; kf++)
            *(v4s*)&sPw[pw[kf]] = p[kf];

#pragma unroll
        for (int ks = 0; ks < 2; ks++) {
            v8bf pb = ldsv8(&sPw[pr[ks]]);
#pragma unroll
            for (int c = 0; c < 8; c++) {
                v8bf av = ldsv8(&sV[(c * 16 + qcol) * 64 + (((ks * 4 + quad) ^ (qcol & 7)) * 8)]);
                acc[c] = __builtin_amdgcn_mfma_f32_16x16x32_bf16(av, pb, acc[c], 0, 0, 0);
            }
        }
    }

    float rl = 1.0f / l_i;
    float* op = out + (size_t)(b * SS + q0 + qcol) * DD + h * DHD;
#pragma unroll
    for (int c = 0; c < 8; c++)
#pragma unroll
        for (int r = 0; r < 4; r++)
            op[c * 16 + quad * 4 + r] = acc[c][r] * rl;
}

// ---------------------------------------------------------------------------
// Launch. ws layout (needs 120 MB):
//   wq @ 0 MB (8) | wk @ 8 (8) | wv @ 16 (8) | qh @ 24 (32) | kh @ 56 (32)
//   | vt @ 88 (32)
// 3 dispatches total: wtrans_all, gemm_all, attn_kernel.
// ---------------------------------------------------------------------------
extern "C" void kernel_launch(void* const* d_in, const int* in_sizes, int n_in,
                              void* d_out, int out_size, void* d_ws, size_t ws_size,
                              hipStream_t stream) {
    const float* q  = (const float*)d_in[0];
    const float* k  = (const float*)d_in[1];
    const float* v  = (const float*)d_in[2];
    const float* Wq = (const float*)d_in[3];
    const float* Wk = (const float*)d_in[4];
    const float* Wv = (const float*)d_in[5];
    char* ws = (char*)d_ws;
    unsigned short* wq  = (unsigned short*)(ws);
    unsigned short* wk  = (unsigned short*)(ws + (size_t)8  * 1024 * 1024);
    unsigned short* wv  = (unsigned short*)(ws + (size_t)16 * 1024 * 1024);
    unsigned short* qhb = (unsigned short*)(ws + (size_t)24 * 1024 * 1024);
    unsigned short* khb = (unsigned short*)(ws + (size_t)56 * 1024 * 1024);
    unsigned short* vtb = (unsigned short*)(ws + (size_t)88 * 1024 * 1024);
    float* out = (float*)d_out;

    wtrans_all<<<dim3(32, 32, 3), dim3(256), 0, stream>>>(Wq, Wk, Wv, wq, wk, wv);
    gemm_all<<<dim3(256, 3), dim3(512), 0, stream>>>(q, k, v, wq, wk, wv, qhb, khb, vtb);
    attn_kernel<<<dim3(SS / 64, HH, BB), dim3(256), 0, stream>>>(qhb, khb, vtb, out);
}